// Round 18
// baseline (632.845 us; speedup 1.0000x reference)
//
#include <hip/hip_runtime.h>

#define T_SEQ 4096
#define HD 2048
#define ID 8192
#define LN_EPS 1e-5f
#define NCH 64           // scan chunks
#define CHL 64           // chunk length (NCH*CHL == T_SEQ)
#define CHSZ ((size_t)NCH * HD)

typedef __attribute__((ext_vector_type(4))) float f32x4;
typedef __attribute__((ext_vector_type(8))) short short8;
typedef __attribute__((ext_vector_type(4))) unsigned short ushort4v;

#define GLB(p) ((const __attribute__((address_space(1))) void*)(p))
#define LDSP(p) ((__attribute__((address_space(3))) void*)(p))

__device__ __forceinline__ unsigned short f2bf(float f) {
  union { float f; unsigned int u; } x; x.f = f;
  unsigned int r = x.u + 0x7fffu + ((x.u >> 16) & 1u);
  return (unsigned short)(r >> 16);
}
__device__ __forceinline__ float bf2f(unsigned short u) {
  union { unsigned int i; float f; } x; x.i = ((unsigned int)u) << 16;
  return x.f;
}

// ---- transpose core: 64x64 tile, 512 threads (64,8), coalesced 128B row writes ----
__device__ __forceinline__ void wt_body(const float* __restrict__ W,
                                        unsigned short* __restrict__ Wt,
                                        int Nfull, int k_base, int n_base, int Kout) {
  __shared__ float tile[64][65];
  int tx = threadIdx.x, ty = threadIdx.y;
  int n0 = blockIdx.x * 64, k0 = blockIdx.y * 64;
#pragma unroll
  for (int j = 0; j < 8; ++j) {
    int k = ty + 8 * j;
    tile[k][tx] = W[(size_t)(k_base + k0 + k) * Nfull + n_base + n0 + tx];
  }
  __syncthreads();
#pragma unroll
  for (int j = 0; j < 8; ++j) {
    int n = ty + 8 * j;
    Wt[(size_t)(n0 + n) * Kout + k0 + tx] = f2bf(tile[tx][n]);
  }
}

__global__ void k_wt(const float* __restrict__ W, unsigned short* __restrict__ Wt) {
  wt_body(W, Wt, HD, 0, 0, HD);
}

__global__ void k_wt4(const float* __restrict__ W0, const float* __restrict__ W1,
                      const float* __restrict__ W2, const float* __restrict__ W3,
                      unsigned short* __restrict__ T) {
  const float* W = W0;
  if (blockIdx.z == 1) W = W1;
  else if (blockIdx.z == 2) W = W2;
  else if (blockIdx.z == 3) W = W3;
  wt_body(W, T + (size_t)blockIdx.z * HD * HD, HD, 0, 0, HD);
}

__global__ void k_wtB(const float* __restrict__ W, unsigned short* __restrict__ Wt,
                      int Nfull, int Kout, int kbz, int nbz, long dstz) {
  int z = blockIdx.z;
  wt_body(W, Wt + (size_t)z * dstz, Nfull, z * kbz, z * nbz, Kout);
}

// ---- row LayerNorm over H=2048, 256 threads/row; y bf16, lastrow f32 ----
__global__ void k_ln(const float* __restrict__ x, const float* __restrict__ sc,
                     const float* __restrict__ bi, unsigned short* __restrict__ y,
                     float* __restrict__ lastrow) {
  int row = blockIdx.x, tid = threadIdx.x;
  const float* xr = x + (size_t)row * HD;
  f32x4 v0 = *(const f32x4*)(xr + tid * 4);
  f32x4 v1 = *(const f32x4*)(xr + 1024 + tid * 4);
  float s = 0.f, s2 = 0.f;
#pragma unroll
  for (int q = 0; q < 4; ++q) { s += v0[q] + v1[q]; s2 += v0[q] * v0[q] + v1[q] * v1[q]; }
#pragma unroll
  for (int o = 32; o; o >>= 1) { s += __shfl_xor(s, o); s2 += __shfl_xor(s2, o); }
  __shared__ float red[8];
  int wv = tid >> 6;
  if ((tid & 63) == 0) { red[wv] = s; red[4 + wv] = s2; }
  __syncthreads();
  if (tid == 0) {
    float a = red[0] + red[1] + red[2] + red[3];
    float b = red[4] + red[5] + red[6] + red[7];
    float mu = a * (1.f / HD);
    float var = b * (1.f / HD) - mu * mu;
    red[0] = mu; red[1] = rsqrtf(var + LN_EPS);
  }
  __syncthreads();
  float mu = red[0], rs = red[1];
  f32x4 s0 = *(const f32x4*)(sc + tid * 4), s1 = *(const f32x4*)(sc + 1024 + tid * 4);
  f32x4 b0 = *(const f32x4*)(bi + tid * 4), b1 = *(const f32x4*)(bi + 1024 + tid * 4);
  float o0[4], o1[4];
  ushort4v y0, y1;
#pragma unroll
  for (int q = 0; q < 4; ++q) {
    o0[q] = (v0[q] - mu) * rs * s0[q] + b0[q];
    o1[q] = (v1[q] - mu) * rs * s1[q] + b1[q];
    y0[q] = f2bf(o0[q]); y1[q] = f2bf(o1[q]);
  }
  unsigned short* yr = y + (size_t)row * HD;
  *(ushort4v*)(yr + tid * 4) = y0;
  *(ushort4v*)(yr + 1024 + tid * 4) = y1;
  if (row == T_SEQ - 1) {
#pragma unroll
    for (int q = 0; q < 4; ++q) {
      lastrow[tid * 4 + q] = o0[q];
      lastrow[1024 + tid * 4 + q] = o1[q];
    }
  }
}

// ---- attention token-shift mix (bf16 x1) -> bf16 kx, vx, rx ----
__global__ void k_mix_att(const unsigned short* __restrict__ x1, const float* __restrict__ sx,
                          const float* __restrict__ tk, const float* __restrict__ tv,
                          const float* __restrict__ tr,
                          unsigned short* __restrict__ kx, unsigned short* __restrict__ vx,
                          unsigned short* __restrict__ rx) {
  size_t idx = ((size_t)blockIdx.x * 256 + threadIdx.x) * 4;
  int h = (int)(idx & (HD - 1));
  ushort4v xu = *(const ushort4v*)(x1 + idx);
  f32x4 x, c;
#pragma unroll
  for (int q = 0; q < 4; ++q) x[q] = bf2f(xu[q]);
  if (idx >= HD) {
    ushort4v cu = *(const ushort4v*)(x1 + idx - HD);
#pragma unroll
    for (int q = 0; q < 4; ++q) c[q] = bf2f(cu[q]);
  } else {
    c = *(const f32x4*)(sx + h);
  }
  f32x4 a = *(const f32x4*)(tk + h);
  f32x4 b = *(const f32x4*)(tv + h);
  f32x4 r = *(const f32x4*)(tr + h);
  ushort4v ok, ov, orr;
#pragma unroll
  for (int q = 0; q < 4; ++q) {
    ok[q] = f2bf(x[q] * a[q] + c[q] * (1.f - a[q]));
    ov[q] = f2bf(x[q] * b[q] + c[q] * (1.f - b[q]));
    orr[q] = f2bf(x[q] * r[q] + c[q] * (1.f - r[q]));
  }
  *(ushort4v*)(kx + idx) = ok;
  *(ushort4v*)(vx + idx) = ov;
  *(ushort4v*)(rx + idx) = orr;
}

// ---- ffn token-shift mix (bf16 x2) -> bf16 fk, fr ----
__global__ void k_mix_ffn(const unsigned short* __restrict__ x2, const float* __restrict__ sx,
                          const float* __restrict__ tk, const float* __restrict__ tr,
                          unsigned short* __restrict__ fk, unsigned short* __restrict__ fr) {
  size_t idx = ((size_t)blockIdx.x * 256 + threadIdx.x) * 4;
  int h = (int)(idx & (HD - 1));
  ushort4v xu = *(const ushort4v*)(x2 + idx);
  f32x4 x, c;
#pragma unroll
  for (int q = 0; q < 4; ++q) x[q] = bf2f(xu[q]);
  if (idx >= HD) {
    ushort4v cu = *(const ushort4v*)(x2 + idx - HD);
#pragma unroll
    for (int q = 0; q < 4; ++q) c[q] = bf2f(cu[q]);
  } else {
    c = *(const f32x4*)(sx + h);
  }
  f32x4 a = *(const f32x4*)(tk + h);
  f32x4 r = *(const f32x4*)(tr + h);
  ushort4v ok, orr;
#pragma unroll
  for (int q = 0; q < 4; ++q) {
    ok[q] = f2bf(x[q] * a[q] + c[q] * (1.f - a[q]));
    orr[q] = f2bf(x[q] * r[q] + c[q] * (1.f - r[q]));
  }
  *(ushort4v*)(fk + idx) = ok;
  *(ushort4v*)(fr + idx) = orr;
}

// ---- WKV blocked scan passes ----
__global__ void k_scan1(const unsigned short* __restrict__ kb,
                        const unsigned short* __restrict__ vb,
                        const float* __restrict__ td, float* __restrict__ scr) {
  int c = blockIdx.x >> 3;
  int h = (blockIdx.x & 7) * 256 + threadIdx.x;
  float wd = -__expf(td[h]);
  float a = 0.f, b = 0.f, p = -1e30f;
  size_t base = (size_t)c * CHL * HD + h;
#pragma unroll 4
  for (int u = 0; u < CHL; ++u) {
    float kk = bf2f(kb[base]), vv = bf2f(vb[base]);
    base += HD;
    float ww2 = wd + p;
    float p2 = fmaxf(ww2, kk);
    float e1 = __expf(ww2 - p2), e2 = __expf(kk - p2);
    a = e1 * a + e2 * vv;
    b = e1 * b + e2;
    p = p2;
  }
  size_t i = (size_t)c * HD + h;
  scr[i] = a;
  scr[CHSZ + i] = b;
  scr[2 * CHSZ + i] = p;
}

__global__ void k_scan2(const float* __restrict__ scr, float* __restrict__ stscr,
                        const float* __restrict__ aa0, const float* __restrict__ bb0,
                        const float* __restrict__ pp0, const float* __restrict__ td,
                        float* __restrict__ st) {
  int h = blockIdx.x * 256 + threadIdx.x;
  float aa = aa0[h], bb = bb0[h], pp = pp0[h];
  float wdL = -__expf(td[h]) * (float)CHL;
  for (int c = 0; c < NCH; ++c) {
    size_t i = (size_t)c * HD + h;
    stscr[i] = aa;
    stscr[CHSZ + i] = bb;
    stscr[2 * CHSZ + i] = pp;
    float ca = scr[i], cb = scr[CHSZ + i], cp = scr[2 * CHSZ + i];
    float ww2 = wdL + pp;
    float p2 = fmaxf(ww2, cp);
    float e1 = __expf(ww2 - p2), e2 = __expf(cp - p2);
    aa = e1 * aa + e2 * ca;
    bb = e1 * bb + e2 * cb;
    pp = p2;
  }
  st[HD + h] = aa;
  st[2 * HD + h] = bb;
  st[3 * HD + h] = pp;
}

__global__ void k_scan3(const unsigned short* __restrict__ kb,
                        const unsigned short* __restrict__ vb,
                        const unsigned short* __restrict__ rb,
                        const float* __restrict__ tf_, const float* __restrict__ td,
                        const float* __restrict__ stscr, unsigned short* __restrict__ rcx) {
  int c = blockIdx.x >> 3;
  int h = (blockIdx.x & 7) * 256 + threadIdx.x;
  size_t i0 = (size_t)c * HD + h;
  float aa = stscr[i0], bb = stscr[CHSZ + i0], pp = stscr[2 * CHSZ + i0];
  float tf = tf_[h];
  float wd = -__expf(td[h]);
  size_t base = (size_t)c * CHL * HD + h;
#pragma unroll 4
  for (int u = 0; u < CHL; ++u) {
    float kk = bf2f(kb[base]), vv = bf2f(vb[base]), rv = bf2f(rb[base]);
    float ww = tf + kk;
    float p = fmaxf(pp, ww);
    float e1 = __expf(pp - p), e2 = __expf(ww - p);
    float cx = (e1 * aa + e2 * vv) / (e1 * bb + e2);
    rcx[base] = f2bf(rv * cx);
    float ww2 = wd + pp;
    float p2 = fmaxf(ww2, kk);
    float e1b = __expf(ww2 - p2), e2b = __expf(kk - p2);
    aa = e1b * aa + e2b * vv;
    bb = e1b * bb + e2b;
    pp = p2;
    base += HD;
  }
}

// ---- fv split-K reduction: out += p0 + p1 (rr already folded into partials) ----
__global__ void k_fvred(float* __restrict__ out, const unsigned short* __restrict__ p0,
                        const unsigned short* __restrict__ p1) {
  size_t i = ((size_t)blockIdx.x * 256 + threadIdx.x) * 4;
  f32x4 o = *(f32x4*)(out + i);
  ushort4v a = *(const ushort4v*)(p0 + i);
  ushort4v b = *(const ushort4v*)(p1 + i);
#pragma unroll
  for (int q = 0; q < 4; ++q) o[q] += bf2f(a[q]) + bf2f(b[q]);
  *(f32x4*)(out + i) = o;
}

// ==== shared 8-phase GEMM machinery (T2 swizzle + T3/T4 counted vmcnt + T5) ====
#define MFMA_Q(mh, nh, bset)                                                   \
  _Pragma("unroll") for (int i_ = 0; i_ < 4; ++i_)                             \
  _Pragma("unroll") for (int j_ = 0; j_ < 2; ++j_)                             \
  _Pragma("unroll") for (int ks_ = 0; ks_ < 2; ++ks_)                          \
    acc[(mh)*4 + i_][(nh)*2 + j_] = __builtin_amdgcn_mfma_f32_16x16x32_bf16(   \
        aS[i_ * 2 + ks_], bset[j_ * 2 + ks_], acc[(mh)*4 + i_][(nh)*2 + j_], 0, 0, 0);

#define RD_A(mh)                                                               \
  { const char* pa_ = Ab + arow0 + (mh)*8192;                                  \
    aS[0] = *(const short8*)(pa_ + 0 * 2048 + swz0);                           \
    aS[1] = *(const short8*)(pa_ + 0 * 2048 + swz1);                           \
    aS[2] = *(const short8*)(pa_ + 1 * 2048 + swz0);                           \
    aS[3] = *(const short8*)(pa_ + 1 * 2048 + swz1);                           \
    aS[4] = *(const short8*)(pa_ + 2 * 2048 + swz0);                           \
    aS[5] = *(const short8*)(pa_ + 2 * 2048 + swz1);                           \
    aS[6] = *(const short8*)(pa_ + 3 * 2048 + swz0);                           \
    aS[7] = *(const short8*)(pa_ + 3 * 2048 + swz1); }

#define RD_B(arr, nh)                                                          \
  { const char* pb_ = Bb + brow0 + (nh)*4096;                                  \
    arr[0] = *(const short8*)(pb_ + 0 * 2048 + swz0);                          \
    arr[1] = *(const short8*)(pb_ + 0 * 2048 + swz1);                          \
    arr[2] = *(const short8*)(pb_ + 1 * 2048 + swz0);                          \
    arr[3] = *(const short8*)(pb_ + 1 * 2048 + swz1); }

// ==== 256x256 8-phase GEMM, BK=64, 8 waves, 128KB LDS dbuf ====
// EPI: 2=relu^2->bf16, 8=kvr merged (z selects triple; z==2 sigmoid->bf16),
//      10=split-K partial with rr fold (z selects K-half; Cb/Cb1 = bf16(rr*acc)),
//      12=fk+fr merged (y<32: fk relu^2->Cb N=8192; y>=32: fr sigmoid->Cb1 N=2048)
template <int EPI>
__global__ __launch_bounds__(512, 2) void k_gemm256(
    const unsigned short* __restrict__ A, const unsigned short* __restrict__ A1,
    const unsigned short* __restrict__ A2,
    const unsigned short* __restrict__ Bt, const unsigned short* __restrict__ Bt1,
    const unsigned short* __restrict__ Bt2,
    int M, int N, int K, int lda, int ldb,
    unsigned short* __restrict__ Cb, unsigned short* __restrict__ Cb1,
    unsigned short* __restrict__ Cb2, const unsigned short* __restrict__ E0b) {
  int koff = 0;
  int by = blockIdx.y;
  bool frp = false;
  if (EPI == 10) {
    koff = blockIdx.z * K;
    if (blockIdx.z) Cb = Cb1;
  } else if (EPI == 12) {
    if (by >= 32) { frp = true; by -= 32; A = A1; Bt = Bt1; Cb = Cb1; N = 2048; }
  } else {
    if (blockIdx.z == 1) { A = A1; Bt = Bt1; Cb = Cb1; }
    else if (blockIdx.z == 2) { A = A2; Bt = Bt2; Cb = Cb2; }
  }
  __shared__ char lds[131072];
  int tid = threadIdx.x;
  int wid = tid >> 6, lane = tid & 63;
  int row_l = lane & 15, kg = lane >> 4;
  int warp_m = wid >> 2, warp_n = wid & 3;
  int m0 = blockIdx.x * 256, n0 = by * 256;

  f32x4 acc[8][4];
#pragma unroll
  for (int i = 0; i < 8; ++i)
#pragma unroll
    for (int j = 0; j < 4; ++j)
#pragma unroll
      for (int q = 0; q < 4; ++q) acc[i][j][q] = 0.f;

  int srow = tid >> 3;
  int schunk = (tid & 7) ^ (srow & 7);
  const unsigned short* Asrc = A + (size_t)(m0 + srow) * lda + koff + schunk * 8;
  const unsigned short* Bsrc = Bt + (size_t)(n0 + srow) * ldb + koff + schunk * 8;
  char* ldsw = lds + wid * 1024;

  auto STAGE_A = [&](int d, int kt) {
#pragma unroll
    for (int h = 0; h < 2; ++h) {
      const unsigned short* s = Asrc + (size_t)(h * 128) * lda + kt;
      char* dst = ldsw + d * 65536 + h * 16384;
      __builtin_amdgcn_global_load_lds(GLB(s), LDSP(dst), 16, 0, 0);
      __builtin_amdgcn_global_load_lds(GLB(s + (size_t)64 * lda), LDSP(dst + 8192), 16, 0, 0);
    }
  };
  auto STAGE_B = [&](int d, int kt) {
#pragma unroll
    for (int h = 0; h < 2; ++h) {
      const unsigned short* s = Bsrc + (size_t)(h * 128) * ldb + kt;
      char* dst = ldsw + d * 65536 + 32768 + h * 16384;
      __builtin_amdgcn_global_load_lds(GLB(s), LDSP(dst), 16, 0, 0);
      __builtin_amdgcn_global_load_lds(GLB(s + (size_t)64 * ldb), LDSP(dst + 8192), 16, 0, 0);
    }
  };

  int swz0 = ((kg) ^ (row_l & 7)) << 4;
  int swz1 = ((4 + kg) ^ (row_l & 7)) << 4;
  int arow0 = (warp_m * 128 + row_l) * 128;
  int brow0 = (warp_n * 64 + row_l) * 128;

  short8 aS[8], b0[4], b1[4];
  int nt = K >> 6;
  STAGE_A(0, 0);
  STAGE_B(0, 0);

#pragma unroll 1
  for (int t = 0; t < nt; ++t) {
    int d = t & 1;
    const char* Ab = lds + d * 65536;
    const char* Bb = lds + d * 65536 + 32768;
    bool pre = (t + 1 < nt);
    int kn = (t + 1) << 6;
    if (pre) {
      STAGE_A(d ^ 1, kn);
      asm volatile("s_waitcnt vmcnt(4)" ::: "memory");
    } else {
      asm volatile("s_waitcnt vmcnt(0)" ::: "memory");
    }
    __builtin_amdgcn_s_barrier();
    RD_A(0)
    RD_B(b0, 0)
    asm volatile("s_waitcnt lgkmcnt(0)" ::: "memory");
    __builtin_amdgcn_s_setprio(1);
    MFMA_Q(0, 0, b0)
    __builtin_amdgcn_s_setprio(0);
    __builtin_amdgcn_s_barrier();
    if (pre) STAGE_B(d ^ 1, kn);
    RD_B(b1, 1)
    asm volatile("s_waitcnt lgkmcnt(0)" ::: "memory");
    __builtin_amdgcn_s_setprio(1);
    MFMA_Q(0, 1, b1)
    __builtin_amdgcn_s_setprio(0);
    __builtin_amdgcn_s_barrier();
    RD_A(1)
    asm volatile("s_waitcnt lgkmcnt(0)" ::: "memory");
    __builtin_amdgcn_s_setprio(1);
    MFMA_Q(1, 1, b1)
    __builtin_amdgcn_s_setprio(0);
    __builtin_amdgcn_s_barrier();
    __builtin_amdgcn_s_setprio(1);
    MFMA_Q(1, 0, b0)
    __builtin_amdgcn_s_setprio(0);
    __builtin_amdgcn_s_barrier();
  }

#pragma unroll
  for (int i = 0; i < 8; ++i) {
#pragma unroll
    for (int j = 0; j < 4; ++j) {
#pragma unroll
      for (int q = 0; q < 4; ++q) {
        int r = m0 + warp_m * 128 + i * 16 + kg * 4 + q;
        int c = n0 + warp_n * 64 + j * 16 + row_l;
        size_t idx = (size_t)r * N + c;
        float val = acc[i][j][q];
        if (EPI == 2) { float t2 = val > 0.f ? val * val : 0.f; Cb[idx] = f2bf(t2); }
        if (EPI == 8) {
          float o = (blockIdx.z == 2) ? 1.f / (1.f + __expf(-val)) : val;
          Cb[idx] = f2bf(o);
        }
        if (EPI == 10) Cb[idx] = f2bf(bf2f(E0b[idx]) * val);
        if (EPI == 12) {
          float o = frp ? 1.f / (1.f + __expf(-val))
                        : (val > 0.f ? val * val : 0.f);
          Cb[idx] = f2bf(o);
        }
      }
    }
  }
}

// ==== 128x256 GEMM, BK=64, 8 waves (2x4), 3-buffer 144KB LDS ring ====
// EPI: 3=C=acc+E0+bf(E1b), 6=sigmoid->bf16, 7=C+=bf(E0b)*acc
template <int EPI>
__global__ __launch_bounds__(512) void k_gemmB(
    const unsigned short* __restrict__ A, const unsigned short* __restrict__ Bt,
    int M, int N, int K, int lda, float* __restrict__ C,
    unsigned short* __restrict__ Cb, const float* __restrict__ E0,
    const unsigned short* __restrict__ E1b, const unsigned short* __restrict__ E0b) {
  __shared__ char lds[147456];  // 3 bufs x (A 16K + B 32K)
  int tid = threadIdx.x;
  int wid = tid >> 6, lane = tid & 63;
  int row_l = lane & 15, kg = lane >> 4;
  int warp_m = wid >> 2, warp_n = wid & 3;   // 2 x 4 waves, 64x64 out each
  int m0 = blockIdx.x * 128, n0 = blockIdx.y * 256;

  f32x4 acc[4][4];
#pragma unroll
  for (int i = 0; i < 4; ++i)
#pragma unroll
    for (int j = 0; j < 4; ++j)
#pragma unroll
      for (int q = 0; q < 4; ++q) acc[i][j][q] = 0.f;

  int srow = tid >> 3;
  int schunk = (tid & 7) ^ (srow & 7);
  const unsigned short* Asrc = A + (size_t)(m0 + srow) * lda + schunk * 8;
  const unsigned short* Bsrc = Bt + (size_t)(n0 + srow) * K + schunk * 8;
  int wsw = wid * 1024;

  auto STAGE_P1 = [&](int d, int kt) {
    char* base = lds + d * 49152;
    __builtin_amdgcn_global_load_lds(GLB(Asrc + kt), LDSP(base + wsw), 16, 0, 0);
    __builtin_amdgcn_global_load_lds(GLB(Asrc + (size_t)64 * lda + kt),
                                     LDSP(base + 8192 + wsw), 16, 0, 0);
    __builtin_amdgcn_global_load_lds(GLB(Bsrc + kt), LDSP(base + 16384 + wsw), 16, 0, 0);
  };
  auto STAGE_P2 = [&](int d, int kt) {
    char* base = lds + d * 49152;
#pragma unroll
    for (int h = 1; h < 4; ++h)
      __builtin_amdgcn_global_load_lds(GLB(Bsrc + (size_t)(h * 64) * K + kt),
                                       LDSP(base + 16384 + h * 8192 + wsw), 16, 0, 0);
  };

  int swz0 = ((kg) ^ (row_l & 7)) << 4;
  int swz1 = ((4 + kg) ^ (row_l & 7)) << 4;
  int arow0 = (warp_m * 64 + row_l) * 128;
  int brow0 = (warp_n * 64 + row_l) * 128;

  short8 aS[8], b0[4], b1[4];
  int nt = K >> 6;
  STAGE_P1(0, 0); STAGE_P2(0, 0);
  STAGE_P1(1, 64); STAGE_P2(1, 64);

#pragma unroll 1
  for (int t = 0; t < nt; ++t) {
    int d = t % 3;
    const char* Ab = lds + d * 49152;
    const char* Bb = lds + d * 49152 + 16384;
    int b2 = t + 2 < nt ? (t + 2) % 3 : 0;
    int k2 = (t + 2) << 6;
    if (t + 2 < nt) {
      STAGE_P1(b2, k2);
      asm volatile("s_waitcnt vmcnt(9)" ::: "memory");
    } else if (t + 1 < nt) {
      asm volatile("s_waitcnt vmcnt(6)" ::: "memory");
    } else {
      asm volatile("s_waitcnt vmcnt(0)" ::: "memory");
    }
    __builtin_amdgcn_s_barrier();
    RD_A(0)
    RD_B(b0, 0)
    asm volatile("s_waitcnt lgkmcnt(0)" ::: "memory");
    __builtin_amdgcn_s_setprio(1);
    MFMA_Q(0, 0, b0)
    __builtin_amdgcn_s_setprio(0);
    __builtin_amdgcn_s_barrier();
    if (t + 2 < nt) STAGE_P2(b2, k2);
    RD_B(b1, 1)
    asm volatile("s_waitcnt lgkmcnt(0)" ::: "memory");
    __builtin_amdgcn_s_setprio(1);
    MFMA_Q(0, 1, b1)
    __builtin_amdgcn_s_setprio(0);
    __builtin_amdgcn_s_barrier();
  }

#pragma unroll
  for (int i = 0; i < 4; ++i) {
#pragma unroll
    for (int j = 0; j < 4; ++j) {
#pragma unroll
      for (int q = 0; q < 4; ++q) {
        int r = m0 + warp_m * 64 + i * 16 + kg * 4 + q;
        int c = n0 + warp_n * 64 + j * 16 + row_l;
        size_t idx = (size_t)r * N + c;
        float val = acc[i][j][q];
        if (EPI == 3) C[idx] = val + E0[idx] + bf2f(E1b[idx]);
        if (EPI == 6) Cb[idx] = f2bf(1.f / (1.f + __expf(-val)));
        if (EPI == 7) C[idx] += bf2f(E0b[idx]) * val;
      }
    }
  }
}

extern "C" void kernel_launch(void* const* d_in, const int* in_sizes, int n_in,
                              void* d_out, int out_size, void* d_ws, size_t ws_size,
                              hipStream_t stream) {
  (void)in_sizes; (void)n_in; (void)out_size;
  const float* hidden     = (const float*)d_in[0];
  const float* att_sx     = (const float*)d_in[1];
  const float* att_aa     = (const float*)d_in[2];
  const float* att_bb     = (const float*)d_in[3];
  const float* att_pp     = (const float*)d_in[4];
  const float* ffd_sx     = (const float*)d_in[5];
  const float* ln1_s      = (const float*)d_in[6];
  const float* ln1_b      = (const float*)d_in[7];
  const float* ln2_s      = (const float*)d_in[8];
  const float* ln2_b      = (const float*)d_in[9];
  const float* time_decay = (const float*)d_in[10];
  const float* time_first = (const float*)d_in[11];
  const float* tm_key     = (const float*)d_in[12];
  const float* tm_value   = (const float*)d_in[13];
  const float* tm_recep   = (const float*)d_in[14];
  const float* Wk         = (const float*)d_in[15];
  const float* Wv         = (const float*)d_in[16];
  const float* Wr         = (const float*)d_in[17];
  const float* Wo         = (const float*)d_in[18];
  const float* ffn_tm_key = (const float*)d_in[19];
  const float* ffn_tm_rec = (const float*)d_in[20];
  const float* Wfk        = (const float*)d_in[21];
  const float* Wfr        = (const float*)d_in[22];
  const float* Wfv        = (const float*)d_in[23];
  float* out = (float*)d_out;
  float* st = out + (size_t)T_SEQ * HD;  // x1last@0, aa@H, bb@2H, pp@3H, x2last@4H

  // ---- arena: 32MB weights + 6 pages + ext(16MB) [+ ext2(16MB) if available] ----
  const size_t MB8 = (size_t)HD * HD * 2;
  const size_t PG = (size_t)T_SEQ * HD * 2;
  char* w = (char*)d_ws;
  unsigned short* s0 = (unsigned short*)(w);
  unsigned short* s1 = (unsigned short*)(w + MB8);
  unsigned short* s2 = (unsigned short*)(w + 2 * MB8);
  unsigned short* s3 = (unsigned short*)(w + 3 * MB8);
  char* pA = w + 4 * MB8;            // kx -> rr
  char* pB = pA + PG;                // vx -> fr(fallback) -> kk2[0]
  char* pC = pB + PG;                // rx -> rcx -> kk2[1]
  char* pD = pC + PG;                // kbf -> x2bf -> kk2[2]
  char* pE = pD + PG;                // x1bf -> kk2[3]
  char* pF = pE + PG;                // vbf -> fk -> fv partial0
  char* ext = w + 4 * MB8 + 6 * PG;  // WfrT -> fv partial1 (16MB)
  char* ext2 = ext + PG;             // fr (merged path only, 16MB)

  unsigned short* kx   = (unsigned short*)pA;
  unsigned short* vx   = (unsigned short*)pB;
  unsigned short* rx   = (unsigned short*)pC;
  unsigned short* kbf  = (unsigned short*)pD;
  unsigned short* x1bf = (unsigned short*)pE;
  unsigned short* vbf  = (unsigned short*)pF;
  unsigned short* rbf  = (unsigned short*)out; // d_out region; dead until o-GEMM
  unsigned short* rcx  = (unsigned short*)pC;
  unsigned short* x2bf = (unsigned short*)pD;
  unsigned short* fk   = (unsigned short*)pF;
  unsigned short* rr   = (unsigned short*)pA;
  unsigned short* kk2  = (unsigned short*)pB;  // 64 MB pB..pE
  unsigned short* wfrT = (unsigned short*)ext; // 8 MB
  unsigned short* pfv0 = (unsigned short*)pF;  // fk dead after fk GEMM
  unsigned short* pfv1 = (unsigned short*)ext; // WfrT dead after fr GEMM
  float* scr   = (float*)s0;
  float* stscr = (float*)s1;
  bool ws144 = ws_size >= (size_t)(4 * MB8 + 7 * PG);   // split-K fv possible
  bool ws160 = ws_size >= (size_t)(4 * MB8 + 8 * PG);   // merged fk+fr possible
  unsigned short* fr = (unsigned short*)(ws160 ? ext2 : pB);

  dim3 tb64(64, 8);
  dim3 wg64(HD / 64, HD / 64);
  dim3 gB(T_SEQ / 128, HD / 256);    // 128x256 tile grid: 256 blocks

  // ---- attention ----
  k_wt4<<<dim3(HD / 64, HD / 64, 4), tb64, 0, stream>>>(Wk, Wv, Wr, Wo, s0);
  k_ln<<<T_SEQ, 256, 0, stream>>>(hidden, ln1_s, ln1_b, x1bf, st);
  k_mix_att<<<T_SEQ * HD / 1024, 256, 0, stream>>>(x1bf, att_sx, tm_key, tm_value, tm_recep,
                                                   kx, vx, rx);
  // merged k+v+r 256^2 8-phase GEMM (384 blocks)
  k_gemm256<8><<<dim3(T_SEQ / 256, HD / 256, 3), 512, 0, stream>>>(
      kx, vx, rx, s0, s1, s2, T_SEQ, HD, HD, HD, HD, kbf, vbf, rbf, nullptr);
  // ---- blocked WKV scan (s0/s1 dead -> scratch) ----
  k_scan1<<<NCH * 8, 256, 0, stream>>>(kbf, vbf, time_decay, scr);
  k_scan2<<<HD / 256, 256, 0, stream>>>(scr, stscr, att_aa, att_bb, att_pp, time_decay, st);
  k_scan3<<<NCH * 8, 256, 0, stream>>>(kbf, vbf, rbf, time_first, time_decay, stscr, rcx);
  // o-proj on 128x256 ring-3 (256 blocks)
  k_gemmB<3><<<gB, 512, 0, stream>>>(rcx, s3, T_SEQ, HD, HD, HD, out, nullptr,
                                     hidden, x1bf, nullptr);

  // ---- feed-forward ----
  k_ln<<<T_SEQ, 256, 0, stream>>>(out, ln2_s, ln2_b, x2bf, st + 4 * HD);
  k_mix_ffn<<<T_SEQ * HD / 1024, 256, 0, stream>>>(x2bf, ffd_sx, ffn_tm_key, ffn_tm_rec,
                                                   fk, fr);
  if (ws160) {
    // merged fk+fr: fr lives in ext2 -> no overlap with kk2 (pB..pE). Audited:
    // inputs fk(pF), fr(ext2), WfkT(s0..s3), WfrT(ext); outputs kk2(pB..pE), rr(pA).
    k_wt<<<wg64, tb64, 0, stream>>>(Wfr, wfrT);
    k_wtB<<<dim3(HD / 64, HD / 64, 4), tb64, 0, stream>>>(Wfk, s0, ID, HD, 0, 2048,
                                                          (long)2048 * 2048);
    k_gemm256<12><<<dim3(T_SEQ / 256, ID / 256 + HD / 256), 512, 0, stream>>>(
        fk, fr, nullptr, s0, wfrT, nullptr, T_SEQ, ID, HD, HD, HD,
        kk2, rr, nullptr, nullptr);
    k_wtB<<<dim3(HD / 64, HD / 64, 4), tb64, 0, stream>>>(Wfv, s0, HD, ID, 2048, 0, 2048);
    k_gemm256<10><<<dim3(T_SEQ / 256, HD / 256, 2), 512, 0, stream>>>(
        kk2, nullptr, nullptr, s0, nullptr, nullptr, T_SEQ, HD, ID / 2, ID, ID,
        pfv0, pfv1, nullptr, rr);
    k_fvred<<<T_SEQ * HD / 1024, 256, 0, stream>>>(out, pfv0, pfv1);
  } else {
    // r16-proven sequence: separate fr GEMM drains pB before kk2 overwrites it
    k_wt<<<wg64, tb64, 0, stream>>>(Wfr, s3);
    k_gemmB<6><<<gB, 512, 0, stream>>>(fr, s3, T_SEQ, HD, HD, HD, nullptr, rr,
                                       nullptr, nullptr, nullptr);
    k_wtB<<<dim3(HD / 64, HD / 64, 4), tb64, 0, stream>>>(Wfk, s0, ID, HD, 0, 2048,
                                                          (long)2048 * 2048);
    k_gemm256<2><<<dim3(T_SEQ / 256, ID / 256), 512, 0, stream>>>(
        fk, nullptr, nullptr, s0, nullptr, nullptr, T_SEQ, ID, HD, HD, HD,
        kk2, nullptr, nullptr, nullptr);
    k_wtB<<<dim3(HD / 64, HD / 64, 4), tb64, 0, stream>>>(Wfv, s0, HD, ID, 2048, 0, 2048);
    if (ws144) {
      k_gemm256<10><<<dim3(T_SEQ / 256, HD / 256, 2), 512, 0, stream>>>(
          kk2, nullptr, nullptr, s0, nullptr, nullptr, T_SEQ, HD, ID / 2, ID, ID,
          pfv0, pfv1, nullptr, rr);
      k_fvred<<<T_SEQ * HD / 1024, 256, 0, stream>>>(out, pfv0, pfv1);
    } else {
      k_gemmB<7><<<gB, 512, 0, stream>>>(kk2, s0, T_SEQ, HD, ID, ID, out, nullptr,
                                         nullptr, nullptr, rr);
    }
  }
}

// Round 19
// 602.845 us; speedup vs baseline: 1.0498x; 1.0498x over previous
//
#include <hip/hip_runtime.h>

#define T_SEQ 4096
#define HD 2048
#define ID 8192
#define LN_EPS 1e-5f
#define NCH 64           // scan chunks
#define CHL 64           // chunk length (NCH*CHL == T_SEQ)
#define CHSZ ((size_t)NCH * HD)

typedef __attribute__((ext_vector_type(4))) float f32x4;
typedef __attribute__((ext_vector_type(8))) short short8;
typedef __attribute__((ext_vector_type(4))) unsigned short ushort4v;

#define GLB(p) ((const __attribute__((address_space(1))) void*)(p))
#define LDSP(p) ((__attribute__((address_space(3))) void*)(p))

__device__ __forceinline__ unsigned short f2bf(float f) {
  union { float f; unsigned int u; } x; x.f = f;
  unsigned int r = x.u + 0x7fffu + ((x.u >> 16) & 1u);
  return (unsigned short)(r >> 16);
}
__device__ __forceinline__ float bf2f(unsigned short u) {
  union { unsigned int i; float f; } x; x.i = ((unsigned int)u) << 16;
  return x.f;
}

// ---- transpose core: 64x64 tile, 512 threads (64,8), coalesced 128B row writes ----
__device__ __forceinline__ void wt_body(const float* __restrict__ W,
                                        unsigned short* __restrict__ Wt,
                                        int Nfull, int k_base, int n_base, int Kout) {
  __shared__ float tile[64][65];
  int tx = threadIdx.x, ty = threadIdx.y;
  int n0 = blockIdx.x * 64, k0 = blockIdx.y * 64;
#pragma unroll
  for (int j = 0; j < 8; ++j) {
    int k = ty + 8 * j;
    tile[k][tx] = W[(size_t)(k_base + k0 + k) * Nfull + n_base + n0 + tx];
  }
  __syncthreads();
#pragma unroll
  for (int j = 0; j < 8; ++j) {
    int n = ty + 8 * j;
    Wt[(size_t)(n0 + n) * Kout + k0 + tx] = f2bf(tile[tx][n]);
  }
}

__global__ void k_wt(const float* __restrict__ W, unsigned short* __restrict__ Wt) {
  wt_body(W, Wt, HD, 0, 0, HD);
}

__global__ void k_wt4(const float* __restrict__ W0, const float* __restrict__ W1,
                      const float* __restrict__ W2, const float* __restrict__ W3,
                      unsigned short* __restrict__ T) {
  const float* W = W0;
  if (blockIdx.z == 1) W = W1;
  else if (blockIdx.z == 2) W = W2;
  else if (blockIdx.z == 3) W = W3;
  wt_body(W, T + (size_t)blockIdx.z * HD * HD, HD, 0, 0, HD);
}

__global__ void k_wtB(const float* __restrict__ W, unsigned short* __restrict__ Wt,
                      int Nfull, int Kout, int kbz, int nbz, long dstz) {
  int z = blockIdx.z;
  wt_body(W, Wt + (size_t)z * dstz, Nfull, z * kbz, z * nbz, Kout);
}

// ---- row LayerNorm over H=2048, 256 threads/row; y bf16, lastrow f32 ----
__global__ void k_ln(const float* __restrict__ x, const float* __restrict__ sc,
                     const float* __restrict__ bi, unsigned short* __restrict__ y,
                     float* __restrict__ lastrow) {
  int row = blockIdx.x, tid = threadIdx.x;
  const float* xr = x + (size_t)row * HD;
  f32x4 v0 = *(const f32x4*)(xr + tid * 4);
  f32x4 v1 = *(const f32x4*)(xr + 1024 + tid * 4);
  float s = 0.f, s2 = 0.f;
#pragma unroll
  for (int q = 0; q < 4; ++q) { s += v0[q] + v1[q]; s2 += v0[q] * v0[q] + v1[q] * v1[q]; }
#pragma unroll
  for (int o = 32; o; o >>= 1) { s += __shfl_xor(s, o); s2 += __shfl_xor(s2, o); }
  __shared__ float red[8];
  int wv = tid >> 6;
  if ((tid & 63) == 0) { red[wv] = s; red[4 + wv] = s2; }
  __syncthreads();
  if (tid == 0) {
    float a = red[0] + red[1] + red[2] + red[3];
    float b = red[4] + red[5] + red[6] + red[7];
    float mu = a * (1.f / HD);
    float var = b * (1.f / HD) - mu * mu;
    red[0] = mu; red[1] = rsqrtf(var + LN_EPS);
  }
  __syncthreads();
  float mu = red[0], rs = red[1];
  f32x4 s0 = *(const f32x4*)(sc + tid * 4), s1 = *(const f32x4*)(sc + 1024 + tid * 4);
  f32x4 b0 = *(const f32x4*)(bi + tid * 4), b1 = *(const f32x4*)(bi + 1024 + tid * 4);
  float o0[4], o1[4];
  ushort4v y0, y1;
#pragma unroll
  for (int q = 0; q < 4; ++q) {
    o0[q] = (v0[q] - mu) * rs * s0[q] + b0[q];
    o1[q] = (v1[q] - mu) * rs * s1[q] + b1[q];
    y0[q] = f2bf(o0[q]); y1[q] = f2bf(o1[q]);
  }
  unsigned short* yr = y + (size_t)row * HD;
  *(ushort4v*)(yr + tid * 4) = y0;
  *(ushort4v*)(yr + 1024 + tid * 4) = y1;
  if (row == T_SEQ - 1) {
#pragma unroll
    for (int q = 0; q < 4; ++q) {
      lastrow[tid * 4 + q] = o0[q];
      lastrow[1024 + tid * 4 + q] = o1[q];
    }
  }
}

// ---- attention token-shift mix (bf16 x1) -> bf16 kx, vx, rx ----
__global__ void k_mix_att(const unsigned short* __restrict__ x1, const float* __restrict__ sx,
                          const float* __restrict__ tk, const float* __restrict__ tv,
                          const float* __restrict__ tr,
                          unsigned short* __restrict__ kx, unsigned short* __restrict__ vx,
                          unsigned short* __restrict__ rx) {
  size_t idx = ((size_t)blockIdx.x * 256 + threadIdx.x) * 4;
  int h = (int)(idx & (HD - 1));
  ushort4v xu = *(const ushort4v*)(x1 + idx);
  f32x4 x, c;
#pragma unroll
  for (int q = 0; q < 4; ++q) x[q] = bf2f(xu[q]);
  if (idx >= HD) {
    ushort4v cu = *(const ushort4v*)(x1 + idx - HD);
#pragma unroll
    for (int q = 0; q < 4; ++q) c[q] = bf2f(cu[q]);
  } else {
    c = *(const f32x4*)(sx + h);
  }
  f32x4 a = *(const f32x4*)(tk + h);
  f32x4 b = *(const f32x4*)(tv + h);
  f32x4 r = *(const f32x4*)(tr + h);
  ushort4v ok, ov, orr;
#pragma unroll
  for (int q = 0; q < 4; ++q) {
    ok[q] = f2bf(x[q] * a[q] + c[q] * (1.f - a[q]));
    ov[q] = f2bf(x[q] * b[q] + c[q] * (1.f - b[q]));
    orr[q] = f2bf(x[q] * r[q] + c[q] * (1.f - r[q]));
  }
  *(ushort4v*)(kx + idx) = ok;
  *(ushort4v*)(vx + idx) = ov;
  *(ushort4v*)(rx + idx) = orr;
}

// ---- ffn token-shift mix (bf16 x2) -> bf16 fk, fr ----
__global__ void k_mix_ffn(const unsigned short* __restrict__ x2, const float* __restrict__ sx,
                          const float* __restrict__ tk, const float* __restrict__ tr,
                          unsigned short* __restrict__ fk, unsigned short* __restrict__ fr) {
  size_t idx = ((size_t)blockIdx.x * 256 + threadIdx.x) * 4;
  int h = (int)(idx & (HD - 1));
  ushort4v xu = *(const ushort4v*)(x2 + idx);
  f32x4 x, c;
#pragma unroll
  for (int q = 0; q < 4; ++q) x[q] = bf2f(xu[q]);
  if (idx >= HD) {
    ushort4v cu = *(const ushort4v*)(x2 + idx - HD);
#pragma unroll
    for (int q = 0; q < 4; ++q) c[q] = bf2f(cu[q]);
  } else {
    c = *(const f32x4*)(sx + h);
  }
  f32x4 a = *(const f32x4*)(tk + h);
  f32x4 r = *(const f32x4*)(tr + h);
  ushort4v ok, orr;
#pragma unroll
  for (int q = 0; q < 4; ++q) {
    ok[q] = f2bf(x[q] * a[q] + c[q] * (1.f - a[q]));
    orr[q] = f2bf(x[q] * r[q] + c[q] * (1.f - r[q]));
  }
  *(ushort4v*)(fk + idx) = ok;
  *(ushort4v*)(fr + idx) = orr;
}

// ---- WKV blocked scan passes ----
__global__ void k_scan1(const unsigned short* __restrict__ kb,
                        const unsigned short* __restrict__ vb,
                        const float* __restrict__ td, float* __restrict__ scr) {
  int c = blockIdx.x >> 3;
  int h = (blockIdx.x & 7) * 256 + threadIdx.x;
  float wd = -__expf(td[h]);
  float a = 0.f, b = 0.f, p = -1e30f;
  size_t base = (size_t)c * CHL * HD + h;
#pragma unroll 4
  for (int u = 0; u < CHL; ++u) {
    float kk = bf2f(kb[base]), vv = bf2f(vb[base]);
    base += HD;
    float ww2 = wd + p;
    float p2 = fmaxf(ww2, kk);
    float e1 = __expf(ww2 - p2), e2 = __expf(kk - p2);
    a = e1 * a + e2 * vv;
    b = e1 * b + e2;
    p = p2;
  }
  size_t i = (size_t)c * HD + h;
  scr[i] = a;
  scr[CHSZ + i] = b;
  scr[2 * CHSZ + i] = p;
}

__global__ void k_scan2(const float* __restrict__ scr, float* __restrict__ stscr,
                        const float* __restrict__ aa0, const float* __restrict__ bb0,
                        const float* __restrict__ pp0, const float* __restrict__ td,
                        float* __restrict__ st) {
  int h = blockIdx.x * 256 + threadIdx.x;
  float aa = aa0[h], bb = bb0[h], pp = pp0[h];
  float wdL = -__expf(td[h]) * (float)CHL;
  for (int c = 0; c < NCH; ++c) {
    size_t i = (size_t)c * HD + h;
    stscr[i] = aa;
    stscr[CHSZ + i] = bb;
    stscr[2 * CHSZ + i] = pp;
    float ca = scr[i], cb = scr[CHSZ + i], cp = scr[2 * CHSZ + i];
    float ww2 = wdL + pp;
    float p2 = fmaxf(ww2, cp);
    float e1 = __expf(ww2 - p2), e2 = __expf(cp - p2);
    aa = e1 * aa + e2 * ca;
    bb = e1 * bb + e2 * cb;
    pp = p2;
  }
  st[HD + h] = aa;
  st[2 * HD + h] = bb;
  st[3 * HD + h] = pp;
}

__global__ void k_scan3(const unsigned short* __restrict__ kb,
                        const unsigned short* __restrict__ vb,
                        const unsigned short* __restrict__ rb,
                        const float* __restrict__ tf_, const float* __restrict__ td,
                        const float* __restrict__ stscr, unsigned short* __restrict__ rcx) {
  int c = blockIdx.x >> 3;
  int h = (blockIdx.x & 7) * 256 + threadIdx.x;
  size_t i0 = (size_t)c * HD + h;
  float aa = stscr[i0], bb = stscr[CHSZ + i0], pp = stscr[2 * CHSZ + i0];
  float tf = tf_[h];
  float wd = -__expf(td[h]);
  size_t base = (size_t)c * CHL * HD + h;
#pragma unroll 4
  for (int u = 0; u < CHL; ++u) {
    float kk = bf2f(kb[base]), vv = bf2f(vb[base]), rv = bf2f(rb[base]);
    float ww = tf + kk;
    float p = fmaxf(pp, ww);
    float e1 = __expf(pp - p), e2 = __expf(ww - p);
    float cx = (e1 * aa + e2 * vv) / (e1 * bb + e2);
    rcx[base] = f2bf(rv * cx);
    float ww2 = wd + pp;
    float p2 = fmaxf(ww2, kk);
    float e1b = __expf(ww2 - p2), e2b = __expf(kk - p2);
    aa = e1b * aa + e2b * vv;
    bb = e1b * bb + e2b;
    pp = p2;
    base += HD;
  }
}

// ---- fv split-K reduction: out += p0 + p1 (rr already folded into partials) ----
__global__ void k_fvred(float* __restrict__ out, const unsigned short* __restrict__ p0,
                        const unsigned short* __restrict__ p1) {
  size_t i = ((size_t)blockIdx.x * 256 + threadIdx.x) * 4;
  f32x4 o = *(f32x4*)(out + i);
  ushort4v a = *(const ushort4v*)(p0 + i);
  ushort4v b = *(const ushort4v*)(p1 + i);
#pragma unroll
  for (int q = 0; q < 4; ++q) o[q] += bf2f(a[q]) + bf2f(b[q]);
  *(f32x4*)(out + i) = o;
}

// ==== shared 8-phase GEMM machinery (T2 swizzle + T3/T4 counted vmcnt + T5) ====
#define MFMA_Q(mh, nh, bset)                                                   \
  _Pragma("unroll") for (int i_ = 0; i_ < 4; ++i_)                             \
  _Pragma("unroll") for (int j_ = 0; j_ < 2; ++j_)                             \
  _Pragma("unroll") for (int ks_ = 0; ks_ < 2; ++ks_)                          \
    acc[(mh)*4 + i_][(nh)*2 + j_] = __builtin_amdgcn_mfma_f32_16x16x32_bf16(   \
        aS[i_ * 2 + ks_], bset[j_ * 2 + ks_], acc[(mh)*4 + i_][(nh)*2 + j_], 0, 0, 0);

#define RD_A(mh)                                                               \
  { const char* pa_ = Ab + arow0 + (mh)*8192;                                  \
    aS[0] = *(const short8*)(pa_ + 0 * 2048 + swz0);                           \
    aS[1] = *(const short8*)(pa_ + 0 * 2048 + swz1);                           \
    aS[2] = *(const short8*)(pa_ + 1 * 2048 + swz0);                           \
    aS[3] = *(const short8*)(pa_ + 1 * 2048 + swz1);                           \
    aS[4] = *(const short8*)(pa_ + 2 * 2048 + swz0);                           \
    aS[5] = *(const short8*)(pa_ + 2 * 2048 + swz1);                           \
    aS[6] = *(const short8*)(pa_ + 3 * 2048 + swz0);                           \
    aS[7] = *(const short8*)(pa_ + 3 * 2048 + swz1); }

#define RD_B(arr, nh)                                                          \
  { const char* pb_ = Bb + brow0 + (nh)*4096;                                  \
    arr[0] = *(const short8*)(pb_ + 0 * 2048 + swz0);                          \
    arr[1] = *(const short8*)(pb_ + 0 * 2048 + swz1);                          \
    arr[2] = *(const short8*)(pb_ + 1 * 2048 + swz0);                          \
    arr[3] = *(const short8*)(pb_ + 1 * 2048 + swz1); }

// ==== 256x256 8-phase GEMM, BK=64, 8 waves, 128KB LDS dbuf ====
// EPI: 2=relu^2->bf16, 8=kvr merged (z selects triple; z==2 sigmoid->bf16),
//      10=split-K partial with rr fold (z selects K-half; Cb/Cb1 = bf16(rr*acc))
template <int EPI>
__global__ __launch_bounds__(512, 2) void k_gemm256(
    const unsigned short* __restrict__ A, const unsigned short* __restrict__ A1,
    const unsigned short* __restrict__ A2,
    const unsigned short* __restrict__ Bt, const unsigned short* __restrict__ Bt1,
    const unsigned short* __restrict__ Bt2,
    int M, int N, int K, int lda, int ldb,
    unsigned short* __restrict__ Cb, unsigned short* __restrict__ Cb1,
    unsigned short* __restrict__ Cb2, const unsigned short* __restrict__ E0b) {
  int koff = 0;
  if (EPI == 10) {
    koff = blockIdx.z * K;
    if (blockIdx.z) Cb = Cb1;
  } else {
    if (blockIdx.z == 1) { A = A1; Bt = Bt1; Cb = Cb1; }
    else if (blockIdx.z == 2) { A = A2; Bt = Bt2; Cb = Cb2; }
  }
  __shared__ char lds[131072];
  int tid = threadIdx.x;
  int wid = tid >> 6, lane = tid & 63;
  int row_l = lane & 15, kg = lane >> 4;
  int warp_m = wid >> 2, warp_n = wid & 3;
  int m0 = blockIdx.x * 256, n0 = blockIdx.y * 256;

  f32x4 acc[8][4];
#pragma unroll
  for (int i = 0; i < 8; ++i)
#pragma unroll
    for (int j = 0; j < 4; ++j)
#pragma unroll
      for (int q = 0; q < 4; ++q) acc[i][j][q] = 0.f;

  int srow = tid >> 3;
  int schunk = (tid & 7) ^ (srow & 7);
  const unsigned short* Asrc = A + (size_t)(m0 + srow) * lda + koff + schunk * 8;
  const unsigned short* Bsrc = Bt + (size_t)(n0 + srow) * ldb + koff + schunk * 8;
  char* ldsw = lds + wid * 1024;

  auto STAGE_A = [&](int d, int kt) {
#pragma unroll
    for (int h = 0; h < 2; ++h) {
      const unsigned short* s = Asrc + (size_t)(h * 128) * lda + kt;
      char* dst = ldsw + d * 65536 + h * 16384;
      __builtin_amdgcn_global_load_lds(GLB(s), LDSP(dst), 16, 0, 0);
      __builtin_amdgcn_global_load_lds(GLB(s + (size_t)64 * lda), LDSP(dst + 8192), 16, 0, 0);
    }
  };
  auto STAGE_B = [&](int d, int kt) {
#pragma unroll
    for (int h = 0; h < 2; ++h) {
      const unsigned short* s = Bsrc + (size_t)(h * 128) * ldb + kt;
      char* dst = ldsw + d * 65536 + 32768 + h * 16384;
      __builtin_amdgcn_global_load_lds(GLB(s), LDSP(dst), 16, 0, 0);
      __builtin_amdgcn_global_load_lds(GLB(s + (size_t)64 * ldb), LDSP(dst + 8192), 16, 0, 0);
    }
  };

  int swz0 = ((kg) ^ (row_l & 7)) << 4;
  int swz1 = ((4 + kg) ^ (row_l & 7)) << 4;
  int arow0 = (warp_m * 128 + row_l) * 128;
  int brow0 = (warp_n * 64 + row_l) * 128;

  short8 aS[8], b0[4], b1[4];
  int nt = K >> 6;
  STAGE_A(0, 0);
  STAGE_B(0, 0);

#pragma unroll 1
  for (int t = 0; t < nt; ++t) {
    int d = t & 1;
    const char* Ab = lds + d * 65536;
    const char* Bb = lds + d * 65536 + 32768;
    bool pre = (t + 1 < nt);
    int kn = (t + 1) << 6;
    if (pre) {
      STAGE_A(d ^ 1, kn);
      asm volatile("s_waitcnt vmcnt(4)" ::: "memory");
    } else {
      asm volatile("s_waitcnt vmcnt(0)" ::: "memory");
    }
    __builtin_amdgcn_s_barrier();
    RD_A(0)
    RD_B(b0, 0)
    asm volatile("s_waitcnt lgkmcnt(0)" ::: "memory");
    __builtin_amdgcn_s_setprio(1);
    MFMA_Q(0, 0, b0)
    __builtin_amdgcn_s_setprio(0);
    __builtin_amdgcn_s_barrier();
    if (pre) STAGE_B(d ^ 1, kn);
    RD_B(b1, 1)
    asm volatile("s_waitcnt lgkmcnt(0)" ::: "memory");
    __builtin_amdgcn_s_setprio(1);
    MFMA_Q(0, 1, b1)
    __builtin_amdgcn_s_setprio(0);
    __builtin_amdgcn_s_barrier();
    RD_A(1)
    asm volatile("s_waitcnt lgkmcnt(0)" ::: "memory");
    __builtin_amdgcn_s_setprio(1);
    MFMA_Q(1, 1, b1)
    __builtin_amdgcn_s_setprio(0);
    __builtin_amdgcn_s_barrier();
    __builtin_amdgcn_s_setprio(1);
    MFMA_Q(1, 0, b0)
    __builtin_amdgcn_s_setprio(0);
    __builtin_amdgcn_s_barrier();
  }

#pragma unroll
  for (int i = 0; i < 8; ++i) {
#pragma unroll
    for (int j = 0; j < 4; ++j) {
#pragma unroll
      for (int q = 0; q < 4; ++q) {
        int r = m0 + warp_m * 128 + i * 16 + kg * 4 + q;
        int c = n0 + warp_n * 64 + j * 16 + row_l;
        size_t idx = (size_t)r * N + c;
        float val = acc[i][j][q];
        if (EPI == 2) { float t2 = val > 0.f ? val * val : 0.f; Cb[idx] = f2bf(t2); }
        if (EPI == 8) {
          float o = (blockIdx.z == 2) ? 1.f / (1.f + __expf(-val)) : val;
          Cb[idx] = f2bf(o);
        }
        if (EPI == 10) Cb[idx] = f2bf(bf2f(E0b[idx]) * val);
      }
    }
  }
}

// ==== 128x256 GEMM, BK=64, 8 waves (2x4), 3-buffer 144KB LDS ring ====
// EPI: 3=C=acc+E0+bf(E1b), 6=sigmoid->bf16, 7=C+=bf(E0b)*acc
template <int EPI>
__global__ __launch_bounds__(512) void k_gemmB(
    const unsigned short* __restrict__ A, const unsigned short* __restrict__ Bt,
    int M, int N, int K, int lda, float* __restrict__ C,
    unsigned short* __restrict__ Cb, const float* __restrict__ E0,
    const unsigned short* __restrict__ E1b, const unsigned short* __restrict__ E0b) {
  __shared__ char lds[147456];  // 3 bufs x (A 16K + B 32K)
  int tid = threadIdx.x;
  int wid = tid >> 6, lane = tid & 63;
  int row_l = lane & 15, kg = lane >> 4;
  int warp_m = wid >> 2, warp_n = wid & 3;   // 2 x 4 waves, 64x64 out each
  int m0 = blockIdx.x * 128, n0 = blockIdx.y * 256;

  f32x4 acc[4][4];
#pragma unroll
  for (int i = 0; i < 4; ++i)
#pragma unroll
    for (int j = 0; j < 4; ++j)
#pragma unroll
      for (int q = 0; q < 4; ++q) acc[i][j][q] = 0.f;

  int srow = tid >> 3;
  int schunk = (tid & 7) ^ (srow & 7);
  const unsigned short* Asrc = A + (size_t)(m0 + srow) * lda + schunk * 8;
  const unsigned short* Bsrc = Bt + (size_t)(n0 + srow) * K + schunk * 8;
  int wsw = wid * 1024;

  auto STAGE_P1 = [&](int d, int kt) {
    char* base = lds + d * 49152;
    __builtin_amdgcn_global_load_lds(GLB(Asrc + kt), LDSP(base + wsw), 16, 0, 0);
    __builtin_amdgcn_global_load_lds(GLB(Asrc + (size_t)64 * lda + kt),
                                     LDSP(base + 8192 + wsw), 16, 0, 0);
    __builtin_amdgcn_global_load_lds(GLB(Bsrc + kt), LDSP(base + 16384 + wsw), 16, 0, 0);
  };
  auto STAGE_P2 = [&](int d, int kt) {
    char* base = lds + d * 49152;
#pragma unroll
    for (int h = 1; h < 4; ++h)
      __builtin_amdgcn_global_load_lds(GLB(Bsrc + (size_t)(h * 64) * K + kt),
                                       LDSP(base + 16384 + h * 8192 + wsw), 16, 0, 0);
  };

  int swz0 = ((kg) ^ (row_l & 7)) << 4;
  int swz1 = ((4 + kg) ^ (row_l & 7)) << 4;
  int arow0 = (warp_m * 64 + row_l) * 128;
  int brow0 = (warp_n * 64 + row_l) * 128;

  short8 aS[8], b0[4], b1[4];
  int nt = K >> 6;
  STAGE_P1(0, 0); STAGE_P2(0, 0);
  STAGE_P1(1, 64); STAGE_P2(1, 64);

#pragma unroll 1
  for (int t = 0; t < nt; ++t) {
    int d = t % 3;
    const char* Ab = lds + d * 49152;
    const char* Bb = lds + d * 49152 + 16384;
    int b2 = t + 2 < nt ? (t + 2) % 3 : 0;
    int k2 = (t + 2) << 6;
    if (t + 2 < nt) {
      STAGE_P1(b2, k2);
      asm volatile("s_waitcnt vmcnt(9)" ::: "memory");
    } else if (t + 1 < nt) {
      asm volatile("s_waitcnt vmcnt(6)" ::: "memory");
    } else {
      asm volatile("s_waitcnt vmcnt(0)" ::: "memory");
    }
    __builtin_amdgcn_s_barrier();
    RD_A(0)
    RD_B(b0, 0)
    asm volatile("s_waitcnt lgkmcnt(0)" ::: "memory");
    __builtin_amdgcn_s_setprio(1);
    MFMA_Q(0, 0, b0)
    __builtin_amdgcn_s_setprio(0);
    __builtin_amdgcn_s_barrier();
    if (t + 2 < nt) STAGE_P2(b2, k2);
    RD_B(b1, 1)
    asm volatile("s_waitcnt lgkmcnt(0)" ::: "memory");
    __builtin_amdgcn_s_setprio(1);
    MFMA_Q(0, 1, b1)
    __builtin_amdgcn_s_setprio(0);
    __builtin_amdgcn_s_barrier();
  }

#pragma unroll
  for (int i = 0; i < 4; ++i) {
#pragma unroll
    for (int j = 0; j < 4; ++j) {
#pragma unroll
      for (int q = 0; q < 4; ++q) {
        int r = m0 + warp_m * 64 + i * 16 + kg * 4 + q;
        int c = n0 + warp_n * 64 + j * 16 + row_l;
        size_t idx = (size_t)r * N + c;
        float val = acc[i][j][q];
        if (EPI == 3) C[idx] = val + E0[idx] + bf2f(E1b[idx]);
        if (EPI == 6) Cb[idx] = f2bf(1.f / (1.f + __expf(-val)));
        if (EPI == 7) C[idx] += bf2f(E0b[idx]) * val;
      }
    }
  }
}

extern "C" void kernel_launch(void* const* d_in, const int* in_sizes, int n_in,
                              void* d_out, int out_size, void* d_ws, size_t ws_size,
                              hipStream_t stream) {
  (void)in_sizes; (void)n_in; (void)out_size;
  const float* hidden     = (const float*)d_in[0];
  const float* att_sx     = (const float*)d_in[1];
  const float* att_aa     = (const float*)d_in[2];
  const float* att_bb     = (const float*)d_in[3];
  const float* att_pp     = (const float*)d_in[4];
  const float* ffd_sx     = (const float*)d_in[5];
  const float* ln1_s      = (const float*)d_in[6];
  const float* ln1_b      = (const float*)d_in[7];
  const float* ln2_s      = (const float*)d_in[8];
  const float* ln2_b      = (const float*)d_in[9];
  const float* time_decay = (const float*)d_in[10];
  const float* time_first = (const float*)d_in[11];
  const float* tm_key     = (const float*)d_in[12];
  const float* tm_value   = (const float*)d_in[13];
  const float* tm_recep   = (const float*)d_in[14];
  const float* Wk         = (const float*)d_in[15];
  const float* Wv         = (const float*)d_in[16];
  const float* Wr         = (const float*)d_in[17];
  const float* Wo         = (const float*)d_in[18];
  const float* ffn_tm_key = (const float*)d_in[19];
  const float* ffn_tm_rec = (const float*)d_in[20];
  const float* Wfk        = (const float*)d_in[21];
  const float* Wfr        = (const float*)d_in[22];
  const float* Wfv        = (const float*)d_in[23];
  float* out = (float*)d_out;
  float* st = out + (size_t)T_SEQ * HD;  // x1last@0, aa@H, bb@2H, pp@3H, x2last@4H

  // ---- 128 MB arena (+16 MB optional split-K partial) ----
  const size_t MB8 = (size_t)HD * HD * 2;
  const size_t PG = (size_t)T_SEQ * HD * 2;
  char* w = (char*)d_ws;
  unsigned short* s0 = (unsigned short*)(w);
  unsigned short* s1 = (unsigned short*)(w + MB8);
  unsigned short* s2 = (unsigned short*)(w + 2 * MB8);
  unsigned short* s3 = (unsigned short*)(w + 3 * MB8);
  char* pA = w + 4 * MB8;            // kx -> rr
  char* pB = pA + PG;                // vx -> fr -> kk2[0]
  char* pC = pB + PG;                // rx -> rcx -> kk2[1]
  char* pD = pC + PG;                // kbf -> x2bf -> kk2[2]
  char* pE = pD + PG;                // x1bf -> kk2[3]
  char* pF = pE + PG;                // vbf -> fk -> fv partial0

  unsigned short* kx   = (unsigned short*)pA;
  unsigned short* vx   = (unsigned short*)pB;
  unsigned short* rx   = (unsigned short*)pC;
  unsigned short* kbf  = (unsigned short*)pD;
  unsigned short* x1bf = (unsigned short*)pE;
  unsigned short* vbf  = (unsigned short*)pF;
  unsigned short* rbf  = (unsigned short*)out; // d_out region; dead until o-GEMM
  unsigned short* rcx  = (unsigned short*)pC;
  unsigned short* x2bf = (unsigned short*)pD;
  unsigned short* fk   = (unsigned short*)pF;
  unsigned short* fr   = (unsigned short*)pB;
  unsigned short* rr   = (unsigned short*)pA;
  unsigned short* kk2  = (unsigned short*)pB;  // 64 MB pB..pE
  unsigned short* pfv0 = (unsigned short*)pF;  // fk dead after fk-GEMM
  unsigned short* pfv1 = (unsigned short*)(w + 4 * MB8 + 6 * PG);  // +16MB ext
  float* scr   = (float*)s0;
  float* stscr = (float*)s1;
  bool big_ws = ws_size >= (size_t)(4 * MB8 + 7 * PG);

  dim3 tb64(64, 8);
  dim3 wg64(HD / 64, HD / 64);
  dim3 gB(T_SEQ / 128, HD / 256);    // 128x256 tile grid: 256 blocks

  // ---- attention ----
  k_wt4<<<dim3(HD / 64, HD / 64, 4), tb64, 0, stream>>>(Wk, Wv, Wr, Wo, s0);
  k_ln<<<T_SEQ, 256, 0, stream>>>(hidden, ln1_s, ln1_b, x1bf, st);
  k_mix_att<<<T_SEQ * HD / 1024, 256, 0, stream>>>(x1bf, att_sx, tm_key, tm_value, tm_recep,
                                                   kx, vx, rx);
  // merged k+v+r 256^2 8-phase GEMM (384 blocks)
  k_gemm256<8><<<dim3(T_SEQ / 256, HD / 256, 3), 512, 0, stream>>>(
      kx, vx, rx, s0, s1, s2, T_SEQ, HD, HD, HD, HD, kbf, vbf, rbf, nullptr);
  // ---- blocked WKV scan (s0/s1 dead -> scratch) ----
  k_scan1<<<NCH * 8, 256, 0, stream>>>(kbf, vbf, time_decay, scr);
  k_scan2<<<HD / 256, 256, 0, stream>>>(scr, stscr, att_aa, att_bb, att_pp, time_decay, st);
  k_scan3<<<NCH * 8, 256, 0, stream>>>(kbf, vbf, rbf, time_first, time_decay, stscr, rcx);
  // o-proj on 128x256 ring-3 (256 blocks)
  k_gemmB<3><<<gB, 512, 0, stream>>>(rcx, s3, T_SEQ, HD, HD, HD, out, nullptr,
                                     hidden, x1bf, nullptr);

  // ---- feed-forward ----
  k_ln<<<T_SEQ, 256, 0, stream>>>(out, ln2_s, ln2_b, x2bf, st + 4 * HD);
  k_mix_ffn<<<T_SEQ * HD / 1024, 256, 0, stream>>>(x2bf, ffd_sx, ffn_tm_key, ffn_tm_rec,
                                                   fk, fr);
  k_wt<<<wg64, tb64, 0, stream>>>(Wfr, s3);
  k_gemmB<6><<<gB, 512, 0, stream>>>(fr, s3, T_SEQ, HD, HD, HD, nullptr, rr,
                                     nullptr, nullptr, nullptr);
  // stage full WfkT [8192][2048] into s0..s3 (one z=4 launch), then fk GEMM (512 blocks)
  k_wtB<<<dim3(HD / 64, HD / 64, 4), tb64, 0, stream>>>(Wfk, s0, ID, HD, 0, 2048,
                                                        (long)2048 * 2048);
  k_gemm256<2><<<dim3(T_SEQ / 256, ID / 256), 512, 0, stream>>>(
      fk, nullptr, nullptr, s0, nullptr, nullptr, T_SEQ, ID, HD, HD, HD,
      kk2, nullptr, nullptr, nullptr);
  // stage full WfvT [2048][8192] into s0..s3 (one z=4 launch)
  k_wtB<<<dim3(HD / 64, HD / 64, 4), tb64, 0, stream>>>(Wfv, s0, HD, ID, 2048, 0, 2048);
  if (big_ws) {
    // fv split-K=2 on 256^2 (grid 16x8x2 = 256 blocks): partials = bf16(rr*acc),
    // then fused reduction out += p0 + p1
    k_gemm256<10><<<dim3(T_SEQ / 256, HD / 256, 2), 512, 0, stream>>>(
        kk2, nullptr, nullptr, s0, nullptr, nullptr, T_SEQ, HD, ID / 2, ID, ID,
        pfv0, pfv1, nullptr, rr);
    k_fvred<<<T_SEQ * HD / 1024, 256, 0, stream>>>(out, pfv0, pfv1);
  } else {
    // fallback: fv on 128x256 ring-3
    k_gemmB<7><<<gB, 512, 0, stream>>>(kk2, s0, T_SEQ, HD, ID, ID, out, nullptr,
                                       nullptr, nullptr, rr);
  }
}